// Round 14
// baseline (142.496 us; speedup 1.0000x reference)
//
#include <hip/hip_runtime.h>

// FNO spectral convolution, truncated separable DFT formulation.
// B=8, H=W=256, C_IN=C_OUT=64, modes 32 x 17 (rows fftshift-centered: k_m = m-16).
//
// Round-14: (1) k3 = r11's s_load radix-4 (hypothesis: r11's regression was
// its k1, not this k3; s_load avoids r13-k3's LDS staging + pipe contention).
// (2) G layout -> [b][n][h][i]: k2a reads become one contiguous 32KB stream
// per block (was 8.7KB-strided); k1 store cost unchanged (17x 512B either way).
// All occupancy/grid parameters unchanged from measured-best r13.
//
// ws layout (floats):
//   twD [64 w'][18 pairs]  : 2304   (cos,sin of +2pi n w'/256; pair 17 = pad)
//   twB [256 h][32 m][2]   : 16384
//   twC [32]               : 32     (2*cos(2pi n/256), n<17)
//   G   [B][17][H][64][2]  : 4456448   (aliased by Z after k2a)
//   T   [B][H][17][64][2]  : 4456448   (aliased by P before k2c)
//   P [4 hq][136 bn][32 m][64 i][2] -> lives in T's slot
//   Z [8 b][17 n][32 m][64 o][2]    -> lives in dead G's slot

#define NB 8
#define NH 256
#define NW 256
#define NC 64
#define NM1 32
#define NM2 17
#define HQ 4

__global__ void k0_tw(float* __restrict__ twD, float* __restrict__ twB,
                      float* __restrict__ twC) {
    const float STEP = 0.02454369260617026f; // 2*pi/256
    int t = blockIdx.x * 256 + threadIdx.x;
    if (t < 64 * 18) {
        int w = t / 18, nn = t % 18;
        if (nn < 17) {
            int ph = (nn * w) & 255;
            float ang = (float)ph * STEP;
            twD[w * 36 + 2 * nn + 0] = cosf(ang);
            twD[w * 36 + 2 * nn + 1] = sinf(ang);
        } else {
            twD[w * 36 + 34] = 0.f;
            twD[w * 36 + 35] = 0.f;
        }
    }
    if (t < 256 * 32) {
        int h = t >> 5, m = t & 31;
        int ph = ((m - 16) * h) & 255; // two's complement & 255 == mod 256
        float ang = (float)ph * STEP;
        twB[t * 2 + 0] = cosf(ang);
        twB[t * 2 + 1] = sinf(ang);
    }
    if (t < 17) {
        twC[t] = 2.0f * cosf((float)t * STEP);
    }
}

// K1 (real Goertzel, r13 verbatim except G store layout [b][n][h][i]):
// G[n][i] = sum_w x[bh,w,i] cis(-2pi n w/256). s_j = x_j + 2c_n s_{j-1} - s_{j-2};
// fixup Q=(c s63 - s62)+i(sn s63); rotate (-i)^{n(wq+1)}; 4-way LDS reduce.
// 2 rows/block, grid 1024.
__global__ __launch_bounds__(256) void k1_fwdW(const float* __restrict__ x,
                                               const float* __restrict__ twD,
                                               const float* __restrict__ twC,
                                               float* __restrict__ G) {
    __shared__ float lre[4][17][64];
    __shared__ float lim[4][17][64];
    const int tid = threadIdx.x;
    const int i = tid & 63;
    const int wq_u = __builtin_amdgcn_readfirstlane(tid >> 6);
    const int bh0 = blockIdx.x * 2;
    const int b0 = bh0 >> 8;          // h0 = bh0&255, h1 = h0+1 (same b)
    const int h0 = bh0 & 255;

    float twoc[17], cn[17], sn[17];
    #pragma unroll
    for (int n = 0; n < 17; ++n) {
        twoc[n] = twC[n];
        cn[n] = twD[36 + 2 * n];      // row w'=1: cis(2pi n/256)
        sn[n] = twD[36 + 2 * n + 1];
    }

    float s1a[17], s2a[17], s1b[17], s2b[17];
    #pragma unroll
    for (int n = 0; n < 17; ++n) { s1a[n]=0.f; s2a[n]=0.f; s1b[n]=0.f; s2b[n]=0.f; }

    const float* xb0 = x + (size_t)bh0 * (NW * NC) + (size_t)wq_u * 64 * 64 + i;
    const float* xb1 = xb0 + NW * NC;
    #pragma unroll 2
    for (int j = 0; j < 64; j += 2) {
        float x0a = xb0[(size_t)j * 64];
        float x0b = xb0[(size_t)(j + 1) * 64];
        float x1a = xb1[(size_t)j * 64];
        float x1b = xb1[(size_t)(j + 1) * 64];
        #pragma unroll
        for (int n = 0; n < 17; ++n) {
            float ta = fmaf(twoc[n], s1a[n], x0a) - s2a[n];
            float tb = fmaf(twoc[n], ta, x0b) - s1a[n];
            s2a[n] = ta; s1a[n] = tb;
            float ua = fmaf(twoc[n], s1b[n], x1a) - s2b[n];
            float ub = fmaf(twoc[n], ua, x1b) - s1b[n];
            s2b[n] = ua; s1b[n] = ub;
        }
    }

    #pragma unroll
    for (int n = 0; n < 17; ++n) {
        float qr0 = fmaf(cn[n], s1a[n], -s2a[n]);
        float qi0 = sn[n] * s1a[n];
        float qr1 = fmaf(cn[n], s1b[n], -s2b[n]);
        float qi1 = sn[n] * s1b[n];
        int k = (n * (wq_u + 1)) & 3;
        float r0r = (k==0)? qr0 : (k==1)? qi0 : (k==2)? -qr0 : -qi0;
        float r0i = (k==0)? qi0 : (k==1)? -qr0 : (k==2)? -qi0 : qr0;
        float r1r = (k==0)? qr1 : (k==1)? qi1 : (k==2)? -qr1 : -qi1;
        float r1i = (k==0)? qi1 : (k==1)? -qr1 : (k==2)? -qi1 : qr1;
        s1a[n] = r0r; s2a[n] = r0i;
        s1b[n] = r1r; s2b[n] = r1i;
    }

    float2* Gp = (float2*)G;
    #pragma unroll
    for (int n = 0; n < 17; ++n) { lre[wq_u][n][i] = s1a[n]; lim[wq_u][n][i] = s2a[n]; }
    __syncthreads();
    for (int n = wq_u; n < 17; n += 4) {
        float re = (lre[0][n][i] + lre[1][n][i]) + (lre[2][n][i] + lre[3][n][i]);
        float im = (lim[0][n][i] + lim[1][n][i]) + (lim[2][n][i] + lim[3][n][i]);
        Gp[(((size_t)b0 * 17 + n) * 256 + h0) * 64 + i] = make_float2(re, im);
    }
    __syncthreads();
    #pragma unroll
    for (int n = 0; n < 17; ++n) { lre[wq_u][n][i] = s1b[n]; lim[wq_u][n][i] = s2b[n]; }
    __syncthreads();
    for (int n = wq_u; n < 17; n += 4) {
        float re = (lre[0][n][i] + lre[1][n][i]) + (lre[2][n][i] + lre[3][n][i]);
        float im = (lim[0][n][i] + lim[1][n][i]) + (lim[2][n][i] + lim[3][n][i]);
        Gp[(((size_t)b0 * 17 + n) * 256 + (h0 + 1)) * 64 + i] = make_float2(re, im);
    }
}

// K2a: partial H-DFT. grid (136 bn, 4 hq). G now [b][n][h][i]: the 64-h read
// per block is one contiguous 32KB stream.
__global__ __launch_bounds__(256) void k2a_hdft(const float* __restrict__ G,
                                                const float* __restrict__ twB,
                                                float* __restrict__ P) {
    const int bn = blockIdx.x;
    const int b = bn / 17, n = bn % 17;
    const int hq = blockIdx.y;
    const int t = threadIdx.x;
    const int lane = t & 63;
    const int q_u = __builtin_amdgcn_readfirstlane(t >> 6);

    float ar[8], ai[8];
    #pragma unroll
    for (int j = 0; j < 8; ++j) { ar[j] = 0.f; ai[j] = 0.f; }

    const float2* Gb = (const float2*)G + (((size_t)b * 17 + n) * 256 + hq * 64) * 64 + lane;
    #pragma unroll 2
    for (int hh = 0; hh < 64; ++hh) {
        int h = hq * 64 + hh;
        float2 g = Gb[(size_t)hh * 64];               // contiguous stream
        const float* tw = twB + (h * 32 + q_u * 8) * 2;
        #pragma unroll
        for (int j = 0; j < 8; ++j) {
            float c = tw[2 * j], s = tw[2 * j + 1];
            ar[j] = fmaf(g.x, c, fmaf(g.y, s, ar[j]));
            ai[j] = fmaf(g.y, c, fmaf(-g.x, s, ai[j]));
        }
    }
    float2* Pp = (float2*)P + (((size_t)hq * 136 + bn) * 32 + q_u * 8) * 64 + lane;
    #pragma unroll
    for (int j = 0; j < 8; ++j) Pp[j * 64] = make_float2(ar[j], ai[j]);
}

// K2b: 512 threads, wave-per-b. (r10 version, unchanged)
__global__ __launch_bounds__(512) void k2b_mix(const float* __restrict__ P,
                                               const float* __restrict__ Wr,
                                               const float* __restrict__ Wi,
                                               float* __restrict__ Z) {
    __shared__ float2 xs[8 * 64]; // [b][i]
    const int mn = blockIdx.x;
    const int m = mn & 31, n = mn >> 5;
    const int t = threadIdx.x;
    const int lane = t & 63;
    const int q_u = __builtin_amdgcn_readfirstlane(t >> 6); // b for this wave

    {
        int b = t >> 6, i = t & 63;
        const float2* Pp = (const float2*)P + (((size_t)(b * 17 + n)) * 32 + m) * 64 + i;
        float re = 0.f, im = 0.f;
        #pragma unroll
        for (int hq = 0; hq < HQ; ++hq) {
            float2 pv = Pp[(size_t)hq * (136 * 32 * 64)];
            re += pv.x; im += pv.y;
        }
        xs[t] = make_float2(re, im);
    }
    __syncthreads();

    const float scale = (n == 0 ? 1.0f : 2.0f) * (1.0f / 65536.0f);
    float zr = 0.f, zi = 0.f;
    const float* Wrp = Wr + (((size_t)m * 17 + n) * 64) * 64 + lane;
    const float* Wip = Wi + (((size_t)m * 17 + n) * 64) * 64 + lane;
    #pragma unroll 4
    for (int i = 0; i < 64; ++i) {
        float wr = Wrp[(size_t)i * 64], wi = Wip[(size_t)i * 64];
        float2 xv = xs[q_u * 64 + i];  // wave-uniform -> LDS broadcast
        zr = fmaf(xv.x, wr, fmaf(-xv.y, wi, zr));
        zi = fmaf(xv.x, wi, fmaf(xv.y, wr, zi));
    }
    float2* Zp = (float2*)Z;
    Zp[(((size_t)q_u * 17 + n) * 32 + m) * 64 + lane] = make_float2(zr * scale, zi * scale);
}

// K2c: inverse H-DFT. (unchanged; T stays [b][h][n][o])
__global__ __launch_bounds__(256) void k2c_ihdft(const float* __restrict__ Z,
                                                 const float* __restrict__ twB,
                                                 float* __restrict__ T) {
    __shared__ float2 zs[32 * 64];
    const int bn = blockIdx.x;
    const int b = bn / 17, n = bn % 17;
    const int hq = blockIdx.y;
    const int t = threadIdx.x;
    const int lane = t & 63;
    const int q_u = __builtin_amdgcn_readfirstlane(t >> 6);

    const float2* Zp = (const float2*)Z + (((size_t)b * 17 + n) * 32) * 64;
    #pragma unroll
    for (int r = 0; r < 8; ++r) zs[r * 256 + t] = Zp[r * 256 + t];
    __syncthreads();

    float2* Tb = (float2*)T + ((size_t)b * 256 * 17 + n) * 64 + lane;
    #pragma unroll 2
    for (int jj = 0; jj < 8; ++jj) {
        int h = hq * 32 + q_u * 8 + jj;
        const float* tw = twB + h * 64;
        float re0 = 0, im0 = 0, re1 = 0, im1 = 0;
        #pragma unroll
        for (int m = 0; m < 32; m += 2) {
            float2 z0 = zs[m * 64 + lane];
            float c0 = tw[2 * m + 0], s0 = tw[2 * m + 1];
            re0 = fmaf(z0.x, c0, fmaf(-z0.y, s0, re0));
            im0 = fmaf(z0.x, s0, fmaf(z0.y, c0, im0));
            float2 z1 = zs[(m + 1) * 64 + lane];
            float c1 = tw[2 * m + 2], s1 = tw[2 * m + 3];
            re1 = fmaf(z1.x, c1, fmaf(-z1.y, s1, re1));
            im1 = fmaf(z1.x, s1, fmaf(z1.y, c1, im1));
        }
        Tb[(size_t)h * (17 * 64)] = make_float2(re0 + re1, im0 + im1);
    }
}

// K3 (radix-4, s_load twiddles -- r11 version verbatim): y[bh, w'+64j, o] from
// class accumulators A_k = P_k + iQ_k, y(w'+64j) = Re(sum_k i^{jk} A_k);
// Q0,Q2 unused. 2 rows/block, grid 1024; wave q covers w' in [16q,16q+16).
// Per iter: 34-float wave-uniform s_load (8.7KB table, sK$-resident) hidden
// under 232 cyc of VALU; 100 fma + 16 epi + 8 coalesced 256B stores. NO LDS.
__global__ __launch_bounds__(256) void k3_invW(const float* __restrict__ T,
                                               const float* __restrict__ twD,
                                               float* __restrict__ y) {
    const int tid = threadIdx.x;
    const int o = tid & 63;
    const int q_u = __builtin_amdgcn_readfirstlane(tid >> 6);
    const int bh0 = blockIdx.x * 2;

    const float2* T0 = (const float2*)T + (size_t)bh0 * 17 * 64;
    const float2* T1 = T0 + 17 * 64;
    float tr0[17], ti0[17], tr1[17], ti1[17];
    #pragma unroll
    for (int n = 0; n < 17; ++n) {
        float2 v0 = T0[n * 64 + o];
        tr0[n] = v0.x; ti0[n] = v0.y;
        float2 v1 = T1[n * 64 + o];
        tr1[n] = v1.x; ti1[n] = v1.y;
    }

    float* yb0 = y + (size_t)bh0 * (NW * NC) + o;
    float* yb1 = yb0 + NW * NC;
    #pragma unroll 2
    for (int it = 0; it < 16; ++it) {
        const int wp = q_u * 16 + it;
        const float* tw = twD + wp * 36;        // wave-uniform -> s_load
        float P0a=0.f,P1a=0.f,P2a=0.f,P3a=0.f,Q1a=0.f,Q3a=0.f;
        float P0b=0.f,P1b=0.f,P2b=0.f,P3b=0.f,Q1b=0.f,Q3b=0.f;
        #pragma unroll
        for (int n = 0; n < 17; n += 4) {       // k=0: P only
            float c = tw[2 * n], s = tw[2 * n + 1];
            P0a = fmaf(tr0[n], c, fmaf(-ti0[n], s, P0a));
            P0b = fmaf(tr1[n], c, fmaf(-ti1[n], s, P0b));
        }
        #pragma unroll
        for (int n = 2; n < 17; n += 4) {       // k=2: P only
            float c = tw[2 * n], s = tw[2 * n + 1];
            P2a = fmaf(tr0[n], c, fmaf(-ti0[n], s, P2a));
            P2b = fmaf(tr1[n], c, fmaf(-ti1[n], s, P2b));
        }
        #pragma unroll
        for (int n = 1; n < 17; n += 4) {       // k=1: P and Q
            float c = tw[2 * n], s = tw[2 * n + 1];
            P1a = fmaf(tr0[n], c, fmaf(-ti0[n], s, P1a));
            Q1a = fmaf(tr0[n], s, fmaf(ti0[n], c, Q1a));
            P1b = fmaf(tr1[n], c, fmaf(-ti1[n], s, P1b));
            Q1b = fmaf(tr1[n], s, fmaf(ti1[n], c, Q1b));
        }
        #pragma unroll
        for (int n = 3; n < 17; n += 4) {       // k=3: P and Q
            float c = tw[2 * n], s = tw[2 * n + 1];
            P3a = fmaf(tr0[n], c, fmaf(-ti0[n], s, P3a));
            Q3a = fmaf(tr0[n], s, fmaf(ti0[n], c, Q3a));
            P3b = fmaf(tr1[n], c, fmaf(-ti1[n], s, P3b));
            Q3b = fmaf(tr1[n], s, fmaf(ti1[n], c, Q3b));
        }
        // y(w'+64j) = Re(sum_k i^{jk} A_k)
        {
            float s02 = P0a + P2a, d02 = P0a - P2a;
            float s13 = P1a + P3a, dq = Q3a - Q1a;
            yb0[(size_t)wp * 64]         = s02 + s13;
            yb0[(size_t)(wp + 64) * 64]  = d02 + dq;
            yb0[(size_t)(wp + 128) * 64] = s02 - s13;
            yb0[(size_t)(wp + 192) * 64] = d02 - dq;
        }
        {
            float s02 = P0b + P2b, d02 = P0b - P2b;
            float s13 = P1b + P3b, dq = Q3b - Q1b;
            yb1[(size_t)wp * 64]         = s02 + s13;
            yb1[(size_t)(wp + 64) * 64]  = d02 + dq;
            yb1[(size_t)(wp + 128) * 64] = s02 - s13;
            yb1[(size_t)(wp + 192) * 64] = d02 - dq;
        }
    }
}

extern "C" void kernel_launch(void* const* d_in, const int* in_sizes, int n_in,
                              void* d_out, int out_size, void* d_ws, size_t ws_size,
                              hipStream_t stream) {
    (void)in_sizes; (void)n_in; (void)out_size; (void)ws_size;
    const float* x  = (const float*)d_in[0];
    const float* Wr = (const float*)d_in[1];
    const float* Wi = (const float*)d_in[2];
    float* out = (float*)d_out;
    float* ws  = (float*)d_ws;

    float* twD = ws;                 // 2304 floats ([64][36] padded)
    float* twB = ws + 2304;          // 16384 floats
    float* twC = ws + 18688;         // 32 floats
    float* G   = ws + 18720;         // 4456448 floats
    float* T   = G + 4456448;        // 4456448 floats
    float* P   = T;                  // alias: partials live in T's slot
    float* Z   = G;                  // alias: Z lives in dead G's slot

    k0_tw<<<32, 256, 0, stream>>>(twD, twB, twC);
    k1_fwdW<<<NB * NH / 2, 256, 0, stream>>>(x, twD, twC, G);
    k2a_hdft<<<dim3(NB * NM2, HQ), 256, 0, stream>>>(G, twB, P);
    k2b_mix<<<NM1 * NM2, 512, 0, stream>>>(P, Wr, Wi, Z);
    k2c_ihdft<<<dim3(NB * NM2, 8), 256, 0, stream>>>(Z, twB, T);
    k3_invW<<<NB * NH / 2, 256, 0, stream>>>(T, twD, out);
}

// Round 15
// 129.620 us; speedup vs baseline: 1.0993x; 1.0993x over previous
//
#include <hip/hip_runtime.h>

// FNO spectral convolution, truncated separable DFT formulation.
// B=8, H=W=256, C_IN=C_OUT=64, modes 32 x 17 (rows fftshift-centered: k_m = m-16).
//
// Round-15: revert r14 entirely (s_load k3 + G relayout both suspect; r13 is
// the measured-best anchor at 134.3). ONE change vs r13: k3 radix-4 -> radix-8
// fold. Same 34-float LDS row now feeds 16 outputs (2 rows x 8 w-positions):
// LDS reads/output halve (r10/r13 PMC: LDS broadcast issue is k3's binding
// pipe), VALU/output 0.79x. Epilogue with r=sqrt(2)/2 verified term-by-term;
// even-j outputs reduce exactly to the proven radix-4 formulas.
//
// ws layout (floats):
//   twD [64 w'][18 pairs]  : 2304   (cos,sin of +2pi n w'/256; pair 17 = pad)
//   twB [256 h][32 m][2]   : 16384
//   twC [32]               : 32     (2*cos(2pi n/256), n<17)
//   G   [B][H][17][64][2]  : 4456448   (aliased by Z after k2a)
//   T   [B][H][17][64][2]  : 4456448   (aliased by P before k2c)
//   P [4 hq][136 bn][32 m][64 i][2] -> lives in T's slot
//   Z [8 b][17 n][32 m][64 o][2]    -> lives in dead G's slot

#define NB 8
#define NH 256
#define NW 256
#define NC 64
#define NM1 32
#define NM2 17
#define HQ 4

__global__ void k0_tw(float* __restrict__ twD, float* __restrict__ twB,
                      float* __restrict__ twC) {
    const float STEP = 0.02454369260617026f; // 2*pi/256
    int t = blockIdx.x * 256 + threadIdx.x;
    if (t < 64 * 18) {
        int w = t / 18, nn = t % 18;
        if (nn < 17) {
            int ph = (nn * w) & 255;
            float ang = (float)ph * STEP;
            twD[w * 36 + 2 * nn + 0] = cosf(ang);
            twD[w * 36 + 2 * nn + 1] = sinf(ang);
        } else {
            twD[w * 36 + 34] = 0.f;
            twD[w * 36 + 35] = 0.f;
        }
    }
    if (t < 256 * 32) {
        int h = t >> 5, m = t & 31;
        int ph = ((m - 16) * h) & 255; // two's complement & 255 == mod 256
        float ang = (float)ph * STEP;
        twB[t * 2 + 0] = cosf(ang);
        twB[t * 2 + 1] = sinf(ang);
    }
    if (t < 17) {
        twC[t] = 2.0f * cosf((float)t * STEP);
    }
}

// K1 (real Goertzel, r13 verbatim): G[n][i] = sum_w x[bh,w,i] cis(-2pi n w/256).
// s_j = x_j + 2c_n s_{j-1} - s_{j-2}; fixup Q=(c s63 - s62)+i(sn s63);
// rotate (-i)^{n(wq+1)}; 4-way LDS reduce. 2 rows/block, grid 1024.
__global__ __launch_bounds__(256) void k1_fwdW(const float* __restrict__ x,
                                               const float* __restrict__ twD,
                                               const float* __restrict__ twC,
                                               float* __restrict__ G) {
    __shared__ float lre[4][17][64];
    __shared__ float lim[4][17][64];
    const int tid = threadIdx.x;
    const int i = tid & 63;
    const int wq_u = __builtin_amdgcn_readfirstlane(tid >> 6);
    const int bh0 = blockIdx.x * 2;

    float twoc[17], cn[17], sn[17];
    #pragma unroll
    for (int n = 0; n < 17; ++n) {
        twoc[n] = twC[n];
        cn[n] = twD[36 + 2 * n];      // row w'=1: cis(2pi n/256)
        sn[n] = twD[36 + 2 * n + 1];
    }

    float s1a[17], s2a[17], s1b[17], s2b[17];
    #pragma unroll
    for (int n = 0; n < 17; ++n) { s1a[n]=0.f; s2a[n]=0.f; s1b[n]=0.f; s2b[n]=0.f; }

    const float* xb0 = x + (size_t)bh0 * (NW * NC) + (size_t)wq_u * 64 * 64 + i;
    const float* xb1 = xb0 + NW * NC;
    #pragma unroll 2
    for (int j = 0; j < 64; j += 2) {
        float x0a = xb0[(size_t)j * 64];
        float x0b = xb0[(size_t)(j + 1) * 64];
        float x1a = xb1[(size_t)j * 64];
        float x1b = xb1[(size_t)(j + 1) * 64];
        #pragma unroll
        for (int n = 0; n < 17; ++n) {
            float ta = fmaf(twoc[n], s1a[n], x0a) - s2a[n];
            float tb = fmaf(twoc[n], ta, x0b) - s1a[n];
            s2a[n] = ta; s1a[n] = tb;
            float ua = fmaf(twoc[n], s1b[n], x1a) - s2b[n];
            float ub = fmaf(twoc[n], ua, x1b) - s1b[n];
            s2b[n] = ua; s1b[n] = ub;
        }
    }

    #pragma unroll
    for (int n = 0; n < 17; ++n) {
        float qr0 = fmaf(cn[n], s1a[n], -s2a[n]);
        float qi0 = sn[n] * s1a[n];
        float qr1 = fmaf(cn[n], s1b[n], -s2b[n]);
        float qi1 = sn[n] * s1b[n];
        int k = (n * (wq_u + 1)) & 3;
        float r0r = (k==0)? qr0 : (k==1)? qi0 : (k==2)? -qr0 : -qi0;
        float r0i = (k==0)? qi0 : (k==1)? -qr0 : (k==2)? -qi0 : qr0;
        float r1r = (k==0)? qr1 : (k==1)? qi1 : (k==2)? -qr1 : -qi1;
        float r1i = (k==0)? qi1 : (k==1)? -qr1 : (k==2)? -qi1 : qr1;
        s1a[n] = r0r; s2a[n] = r0i;
        s1b[n] = r1r; s2b[n] = r1i;
    }

    #pragma unroll
    for (int n = 0; n < 17; ++n) { lre[wq_u][n][i] = s1a[n]; lim[wq_u][n][i] = s2a[n]; }
    __syncthreads();
    float2* G0 = (float2*)G + (size_t)bh0 * 17 * 64;
    for (int n = wq_u; n < 17; n += 4) {
        float re = (lre[0][n][i] + lre[1][n][i]) + (lre[2][n][i] + lre[3][n][i]);
        float im = (lim[0][n][i] + lim[1][n][i]) + (lim[2][n][i] + lim[3][n][i]);
        G0[n * 64 + i] = make_float2(re, im);
    }
    __syncthreads();
    #pragma unroll
    for (int n = 0; n < 17; ++n) { lre[wq_u][n][i] = s1b[n]; lim[wq_u][n][i] = s2b[n]; }
    __syncthreads();
    float2* G1 = G0 + 17 * 64;
    for (int n = wq_u; n < 17; n += 4) {
        float re = (lre[0][n][i] + lre[1][n][i]) + (lre[2][n][i] + lre[3][n][i]);
        float im = (lim[0][n][i] + lim[1][n][i]) + (lim[2][n][i] + lim[3][n][i]);
        G1[n * 64 + i] = make_float2(re, im);
    }
}

// K2a: partial H-DFT. grid (136 bn, 4 hq). (r13 verbatim)
__global__ __launch_bounds__(256) void k2a_hdft(const float* __restrict__ G,
                                                const float* __restrict__ twB,
                                                float* __restrict__ P) {
    const int bn = blockIdx.x;
    const int b = bn / 17, n = bn % 17;
    const int hq = blockIdx.y;
    const int t = threadIdx.x;
    const int lane = t & 63;
    const int q_u = __builtin_amdgcn_readfirstlane(t >> 6);

    float ar[8], ai[8];
    #pragma unroll
    for (int j = 0; j < 8; ++j) { ar[j] = 0.f; ai[j] = 0.f; }

    const float2* Gb = (const float2*)G + ((size_t)b * 256 * 17 + n) * 64 + lane;
    #pragma unroll 2
    for (int hh = 0; hh < 64; ++hh) {
        int h = hq * 64 + hh;
        float2 g = Gb[(size_t)h * (17 * 64)];
        const float* tw = twB + (h * 32 + q_u * 8) * 2;
        #pragma unroll
        for (int j = 0; j < 8; ++j) {
            float c = tw[2 * j], s = tw[2 * j + 1];
            ar[j] = fmaf(g.x, c, fmaf(g.y, s, ar[j]));
            ai[j] = fmaf(g.y, c, fmaf(-g.x, s, ai[j]));
        }
    }
    float2* Pp = (float2*)P + (((size_t)hq * 136 + bn) * 32 + q_u * 8) * 64 + lane;
    #pragma unroll
    for (int j = 0; j < 8; ++j) Pp[j * 64] = make_float2(ar[j], ai[j]);
}

// K2b: 512 threads, wave-per-b. (r10/r13 version, unchanged)
__global__ __launch_bounds__(512) void k2b_mix(const float* __restrict__ P,
                                               const float* __restrict__ Wr,
                                               const float* __restrict__ Wi,
                                               float* __restrict__ Z) {
    __shared__ float2 xs[8 * 64]; // [b][i]
    const int mn = blockIdx.x;
    const int m = mn & 31, n = mn >> 5;
    const int t = threadIdx.x;
    const int lane = t & 63;
    const int q_u = __builtin_amdgcn_readfirstlane(t >> 6); // b for this wave

    {
        int b = t >> 6, i = t & 63;
        const float2* Pp = (const float2*)P + (((size_t)(b * 17 + n)) * 32 + m) * 64 + i;
        float re = 0.f, im = 0.f;
        #pragma unroll
        for (int hq = 0; hq < HQ; ++hq) {
            float2 pv = Pp[(size_t)hq * (136 * 32 * 64)];
            re += pv.x; im += pv.y;
        }
        xs[t] = make_float2(re, im);
    }
    __syncthreads();

    const float scale = (n == 0 ? 1.0f : 2.0f) * (1.0f / 65536.0f);
    float zr = 0.f, zi = 0.f;
    const float* Wrp = Wr + (((size_t)m * 17 + n) * 64) * 64 + lane;
    const float* Wip = Wi + (((size_t)m * 17 + n) * 64) * 64 + lane;
    #pragma unroll 4
    for (int i = 0; i < 64; ++i) {
        float wr = Wrp[(size_t)i * 64], wi = Wip[(size_t)i * 64];
        float2 xv = xs[q_u * 64 + i];  // wave-uniform -> LDS broadcast
        zr = fmaf(xv.x, wr, fmaf(-xv.y, wi, zr));
        zi = fmaf(xv.x, wi, fmaf(xv.y, wr, zi));
    }
    float2* Zp = (float2*)Z;
    Zp[(((size_t)q_u * 17 + n) * 32 + m) * 64 + lane] = make_float2(zr * scale, zi * scale);
}

// K2c: inverse H-DFT. (r13 verbatim)
__global__ __launch_bounds__(256) void k2c_ihdft(const float* __restrict__ Z,
                                                 const float* __restrict__ twB,
                                                 float* __restrict__ T) {
    __shared__ float2 zs[32 * 64];
    const int bn = blockIdx.x;
    const int b = bn / 17, n = bn % 17;
    const int hq = blockIdx.y;
    const int t = threadIdx.x;
    const int lane = t & 63;
    const int q_u = __builtin_amdgcn_readfirstlane(t >> 6);

    const float2* Zp = (const float2*)Z + (((size_t)b * 17 + n) * 32) * 64;
    #pragma unroll
    for (int r = 0; r < 8; ++r) zs[r * 256 + t] = Zp[r * 256 + t];
    __syncthreads();

    float2* Tb = (float2*)T + ((size_t)b * 256 * 17 + n) * 64 + lane;
    #pragma unroll 2
    for (int jj = 0; jj < 8; ++jj) {
        int h = hq * 32 + q_u * 8 + jj;
        const float* tw = twB + h * 64;
        float re0 = 0, im0 = 0, re1 = 0, im1 = 0;
        #pragma unroll
        for (int m = 0; m < 32; m += 2) {
            float2 z0 = zs[m * 64 + lane];
            float c0 = tw[2 * m + 0], s0 = tw[2 * m + 1];
            re0 = fmaf(z0.x, c0, fmaf(-z0.y, s0, re0));
            im0 = fmaf(z0.x, s0, fmaf(z0.y, c0, im0));
            float2 z1 = zs[(m + 1) * 64 + lane];
            float c1 = tw[2 * m + 2], s1 = tw[2 * m + 3];
            re1 = fmaf(z1.x, c1, fmaf(-z1.y, s1, re1));
            im1 = fmaf(z1.x, s1, fmaf(z1.y, c1, im1));
        }
        Tb[(size_t)h * (17 * 64)] = make_float2(re0 + re1, im0 + im1);
    }
}

// K3 (radix-8 fold + LDS-broadcast twiddles): w = w' + 32j, j in [0,8),
// classes k = n mod 8, A_k = P_k + i Q_k = sum_{n in k} T~_n cis(2pi n w'/256),
// y(w'+32j) = Re(sum_k w8^{jk} A_k), w8 = e^{i pi/4}. Q_0,Q_4 provably unused.
// Even j reduce to the proven radix-4 formulas; odd j use r = sqrt(2)/2:
//   y1 = (D-Hq) + r(G1-G2); y5 = (D-Hq) - r(G1-G2)
//   y3 = (D+Hq) - r(G1+G2); y7 = (D+Hq) + r(G1+G2)
// with D=P0-P4, Hq=Q2-Q6, G1=P1-P3-P5+P7, G2=Q1+Q3-Q5-Q7.
// 2 rows/block, grid 1024; wave q covers w' in [8q, 8q+8). Per iter: 9
// broadcast ds_read_b128 feed 184 VALU + 16 coalesced 256B stores.
__global__ __launch_bounds__(256) void k3_invW(const float* __restrict__ T,
                                               const float* __restrict__ twD,
                                               float* __restrict__ y) {
    __shared__ float tws[32 * 36]; // 4.6 KB (rows w'=0..31 of twD)
    const int tid = threadIdx.x;
    const int o = tid & 63;
    const int q_u = __builtin_amdgcn_readfirstlane(tid >> 6);
    const int bh0 = blockIdx.x * 2;
    const float R8 = 0.7071067811865476f;

    {
        const float4* src = (const float4*)twD;
        float4* dst = (float4*)tws;
        #pragma unroll
        for (int v = tid; v < 288; v += 256) dst[v] = src[v];
    }

    const float2* T0 = (const float2*)T + (size_t)bh0 * 17 * 64;
    const float2* T1 = T0 + 17 * 64;
    float tr0[17], ti0[17], tr1[17], ti1[17];
    #pragma unroll
    for (int n = 0; n < 17; ++n) {
        float2 v0 = T0[n * 64 + o];
        tr0[n] = v0.x; ti0[n] = v0.y;
        float2 v1 = T1[n * 64 + o];
        tr1[n] = v1.x; ti1[n] = v1.y;
    }
    __syncthreads();

    float* yb0 = y + (size_t)bh0 * (NW * NC) + o;
    float* yb1 = yb0 + NW * NC;
    #pragma unroll 1
    for (int it = 0; it < 8; ++it) {
        const int wp = q_u * 8 + it;
        const float* tw = &tws[wp * 36];        // wave-uniform -> broadcast
        float P0a=0,P1a=0,P2a=0,P3a=0,P4a=0,P5a=0,P6a=0,P7a=0;
        float Q1a=0,Q2a=0,Q3a=0,Q5a=0,Q6a=0,Q7a=0;
        float P0b=0,P1b=0,P2b=0,P3b=0,P4b=0,P5b=0,P6b=0,P7b=0;
        float Q1b=0,Q2b=0,Q3b=0,Q5b=0,Q6b=0,Q7b=0;

        #pragma unroll
        for (int n = 0; n < 17; n += 8) {   // k=0: n=0,8,16 (P only)
            float c = tw[2*n], s = tw[2*n+1];
            P0a = fmaf(tr0[n], c, fmaf(-ti0[n], s, P0a));
            P0b = fmaf(tr1[n], c, fmaf(-ti1[n], s, P0b));
        }
        #pragma unroll
        for (int n = 4; n < 17; n += 8) {   // k=4: n=4,12 (P only)
            float c = tw[2*n], s = tw[2*n+1];
            P4a = fmaf(tr0[n], c, fmaf(-ti0[n], s, P4a));
            P4b = fmaf(tr1[n], c, fmaf(-ti1[n], s, P4b));
        }
        #pragma unroll
        for (int n = 1; n < 17; n += 8) {   // k=1: n=1,9
            float c = tw[2*n], s = tw[2*n+1];
            P1a = fmaf(tr0[n], c, fmaf(-ti0[n], s, P1a));
            Q1a = fmaf(tr0[n], s, fmaf( ti0[n], c, Q1a));
            P1b = fmaf(tr1[n], c, fmaf(-ti1[n], s, P1b));
            Q1b = fmaf(tr1[n], s, fmaf( ti1[n], c, Q1b));
        }
        #pragma unroll
        for (int n = 2; n < 17; n += 8) {   // k=2: n=2,10
            float c = tw[2*n], s = tw[2*n+1];
            P2a = fmaf(tr0[n], c, fmaf(-ti0[n], s, P2a));
            Q2a = fmaf(tr0[n], s, fmaf( ti0[n], c, Q2a));
            P2b = fmaf(tr1[n], c, fmaf(-ti1[n], s, P2b));
            Q2b = fmaf(tr1[n], s, fmaf( ti1[n], c, Q2b));
        }
        #pragma unroll
        for (int n = 3; n < 17; n += 8) {   // k=3: n=3,11
            float c = tw[2*n], s = tw[2*n+1];
            P3a = fmaf(tr0[n], c, fmaf(-ti0[n], s, P3a));
            Q3a = fmaf(tr0[n], s, fmaf( ti0[n], c, Q3a));
            P3b = fmaf(tr1[n], c, fmaf(-ti1[n], s, P3b));
            Q3b = fmaf(tr1[n], s, fmaf( ti1[n], c, Q3b));
        }
        #pragma unroll
        for (int n = 5; n < 17; n += 8) {   // k=5: n=5,13
            float c = tw[2*n], s = tw[2*n+1];
            P5a = fmaf(tr0[n], c, fmaf(-ti0[n], s, P5a));
            Q5a = fmaf(tr0[n], s, fmaf( ti0[n], c, Q5a));
            P5b = fmaf(tr1[n], c, fmaf(-ti1[n], s, P5b));
            Q5b = fmaf(tr1[n], s, fmaf( ti1[n], c, Q5b));
        }
        #pragma unroll
        for (int n = 6; n < 17; n += 8) {   // k=6: n=6,14
            float c = tw[2*n], s = tw[2*n+1];
            P6a = fmaf(tr0[n], c, fmaf(-ti0[n], s, P6a));
            Q6a = fmaf(tr0[n], s, fmaf( ti0[n], c, Q6a));
            P6b = fmaf(tr1[n], c, fmaf(-ti1[n], s, P6b));
            Q6b = fmaf(tr1[n], s, fmaf( ti1[n], c, Q6b));
        }
        #pragma unroll
        for (int n = 7; n < 17; n += 8) {   // k=7: n=7,15
            float c = tw[2*n], s = tw[2*n+1];
            P7a = fmaf(tr0[n], c, fmaf(-ti0[n], s, P7a));
            Q7a = fmaf(tr0[n], s, fmaf( ti0[n], c, Q7a));
            P7b = fmaf(tr1[n], c, fmaf(-ti1[n], s, P7b));
            Q7b = fmaf(tr1[n], s, fmaf( ti1[n], c, Q7b));
        }

        // ---- epilogue row 0 ----
        {
            float Se = (P0a + P2a) + (P4a + P6a);
            float So = (P1a + P3a) + (P5a + P7a);
            float C  = (P0a - P2a) + (P4a - P6a);
            float S  = (Q3a - Q1a) + (Q7a - Q5a);
            float D  = P0a - P4a;
            float Hq = Q2a - Q6a;
            float G1 = (P1a - P3a) - (P5a - P7a);
            float G2 = (Q1a + Q3a) - (Q5a + Q7a);
            float u  = R8 * (G1 - G2);
            float v  = R8 * (G1 + G2);
            float dm = D - Hq, dp = D + Hq;
            yb0[(size_t)(wp +   0) * 64] = Se + So;
            yb0[(size_t)(wp +  32) * 64] = dm + u;
            yb0[(size_t)(wp +  64) * 64] = C + S;
            yb0[(size_t)(wp +  96) * 64] = dp - v;
            yb0[(size_t)(wp + 128) * 64] = Se - So;
            yb0[(size_t)(wp + 160) * 64] = dm - u;
            yb0[(size_t)(wp + 192) * 64] = C - S;
            yb0[(size_t)(wp + 224) * 64] = dp + v;
        }
        // ---- epilogue row 1 ----
        {
            float Se = (P0b + P2b) + (P4b + P6b);
            float So = (P1b + P3b) + (P5b + P7b);
            float C  = (P0b - P2b) + (P4b - P6b);
            float S  = (Q3b - Q1b) + (Q7b - Q5b);
            float D  = P0b - P4b;
            float Hq = Q2b - Q6b;
            float G1 = (P1b - P3b) - (P5b - P7b);
            float G2 = (Q1b + Q3b) - (Q5b + Q7b);
            float u  = R8 * (G1 - G2);
            float v  = R8 * (G1 + G2);
            float dm = D - Hq, dp = D + Hq;
            yb1[(size_t)(wp +   0) * 64] = Se + So;
            yb1[(size_t)(wp +  32) * 64] = dm + u;
            yb1[(size_t)(wp +  64) * 64] = C + S;
            yb1[(size_t)(wp +  96) * 64] = dp - v;
            yb1[(size_t)(wp + 128) * 64] = Se - So;
            yb1[(size_t)(wp + 160) * 64] = dm - u;
            yb1[(size_t)(wp + 192) * 64] = C - S;
            yb1[(size_t)(wp + 224) * 64] = dp + v;
        }
    }
}

extern "C" void kernel_launch(void* const* d_in, const int* in_sizes, int n_in,
                              void* d_out, int out_size, void* d_ws, size_t ws_size,
                              hipStream_t stream) {
    (void)in_sizes; (void)n_in; (void)out_size; (void)ws_size;
    const float* x  = (const float*)d_in[0];
    const float* Wr = (const float*)d_in[1];
    const float* Wi = (const float*)d_in[2];
    float* out = (float*)d_out;
    float* ws  = (float*)d_ws;

    float* twD = ws;                 // 2304 floats ([64][36] padded)
    float* twB = ws + 2304;          // 16384 floats
    float* twC = ws + 18688;         // 32 floats
    float* G   = ws + 18720;         // 4456448 floats
    float* T   = G + 4456448;        // 4456448 floats
    float* P   = T;                  // alias: partials live in T's slot
    float* Z   = G;                  // alias: Z lives in dead G's slot

    k0_tw<<<32, 256, 0, stream>>>(twD, twB, twC);
    k1_fwdW<<<NB * NH / 2, 256, 0, stream>>>(x, twD, twC, G);
    k2a_hdft<<<dim3(NB * NM2, HQ), 256, 0, stream>>>(G, twB, P);
    k2b_mix<<<NM1 * NM2, 512, 0, stream>>>(P, Wr, Wi, Z);
    k2c_ihdft<<<dim3(NB * NM2, 8), 256, 0, stream>>>(Z, twB, T);
    k3_invW<<<NB * NH / 2, 256, 0, stream>>>(T, twD, out);
}